// Round 5
// baseline (540.216 us; speedup 1.0000x reference)
//
#include <hip/hip_runtime.h>

#define T_STEPS 512
#define IN_DIM 11
#define ROW_PAD 12                  // x row padded to 12 floats in LDS
#define H_DIM 16
#define ROW_F (T_STEPS * IN_DIM)    // 5632 floats per batch row
#define CHUNK_T 16                  // t-steps per chunk (pipeline granule)
#define CHUNK_F (CHUNK_T * IN_DIM)  // 176 source floats per chunk
#define N_CHUNK (T_STEPS / CHUNK_T)
#define LOG2E 1.44269504088896340736f

typedef float v2f __attribute__((ext_vector_type(2)));
typedef float v4f __attribute__((ext_vector_type(4)));

// Packed fp32 FMA (v_pk_fma_f32): 2 MACs/instr, full rate.
__device__ __forceinline__ v2f pk_fma(v2f a, v2f b, v2f c) {
    v2f d;
    asm("v_pk_fma_f32 %0, %1, %2, %3" : "=v"(d) : "v"(a), "v"(b), "v"(c));
    return d;
}

// DPP quad_perm broadcast within each group of 4 lanes.
template<int CTRL>
__device__ __forceinline__ float qperm(float v) {
    return __builtin_bit_cast(float,
        __builtin_amdgcn_update_dpp(0, __builtin_bit_cast(int, v),
                                    CTRL, 0xf, 0xf, true));
}

__device__ __forceinline__ float bcast_lane(float v, int l) {
    return __builtin_bit_cast(float,
        __builtin_amdgcn_readlane(__builtin_bit_cast(int, v), l));
}

// ds_swizzle xor within 32-lane groups (BitMode: and=0x1F, or=0, xor=mask).
template<int PAT>
__device__ __forceinline__ float swz(float v) {
    return __builtin_bit_cast(float,
        __builtin_amdgcn_ds_swizzle(__builtin_bit_cast(int, v), PAT));
}

// ds_bpermute pull: result = value of lane (addr>>2). addr precomputed in bytes.
__device__ __forceinline__ float bperm(int addr, float v) {
    return __builtin_bit_cast(float,
        __builtin_amdgcn_ds_bpermute(addr, __builtin_bit_cast(int, v)));
}

// Quarter-split recurrent dot, fully in-register (no LDS h round trip).
// Each lane holds hv = h[r] (quad-replicated). 3 ds_swizzle xor{4,8,12}
// gather the lane's 4-value h group; lane computes 4 partial dots (own row
// + rows of lanes ^16/^32/^48, per-lane weight constants); 3 ds_bpermute
// exchange the scalar partials. Result = bias + sum_k Wrec[row,k]*h[k].
__device__ __forceinline__ float rec_dot(float hv,
        const v2f wq0[2], const v2f wq1[2], const v2f wq2[2], const v2f wq3[2],
        float bias, int a16, int a32, int a48) {
    const float g1 = swz<0x101F>(hv);   // h[rbase | (q^1)]
    const float g2 = swz<0x201F>(hv);   // h[rbase | (q^2)]
    const float g3 = swz<0x301F>(hv);   // h[rbase | (q^3)]
    const v2f hp0 = (v2f){hv, g1};
    const v2f hp1 = (v2f){g2, g3};
    v2f d0 = pk_fma(wq0[0], hp0, (v2f){bias, 0.f});
    d0 = pk_fma(wq0[1], hp1, d0);
    v2f d1 = pk_fma(wq1[0], hp0, (v2f){0.f, 0.f});
    d1 = pk_fma(wq1[1], hp1, d1);
    v2f d2 = pk_fma(wq2[0], hp0, (v2f){0.f, 0.f});
    d2 = pk_fma(wq2[1], hp1, d2);
    v2f d3 = pk_fma(wq3[0], hp0, (v2f){0.f, 0.f});
    d3 = pk_fma(wq3[1], hp1, d3);
    const float r1 = bperm(a16, d1.x + d1.y);   // partial for my row from lane^16
    const float r2 = bperm(a32, d2.x + d2.y);   // from lane^32
    const float r3 = bperm(a48, d3.x + d3.y);   // from lane^48
    return (d0.x + d0.y) + r1 + r2 + r3;
}

// LSTM activation step: gsum -> gates -> cell update -> h out.
#define ACT_STEP(gsum, cst, hv_out)                                           \
    {                                                                         \
        const float a_ = __builtin_fmaf(vAa,                                  \
            __builtin_amdgcn_rcpf(1.0f + __builtin_amdgcn_exp2f(gsum)), vBc); \
        const float gi_ = qperm<0x00>(a_);                                    \
        const float gf_ = qperm<0x55>(a_);                                    \
        const float gg_ = qperm<0xAA>(a_);                                    \
        const float go_ = qperm<0xFF>(a_);                                    \
        cst = __builtin_fmaf(gf_, cst, gi_ * gg_);                            \
        const float tc_ = __builtin_fmaf(2.0f,                                \
            __builtin_amdgcn_rcpf(1.0f +                                      \
                __builtin_amdgcn_exp2f(-2.0f * LOG2E * cst)), -1.0f);         \
        hv_out = go_ * tc_;                                                   \
    }

// LAYER-PIPELINED 2-layer LSTM, register-resident recurrence.
// Block = 256 threads = 4 waves = 2 batches x {L1-wave, L2-wave}.
// ROUND-4 POST-MORTEM: no spill (52 VGPR, clean counters) but 438us >
// round-1's 390us: still latency-bound (real issue ~35%); the LDS h
// write->read round trip (~240cy lgkm) sat inside BOTH halves' serial
// chains. This round removes LDS from the recurrence entirely via the
// quarter-split dot (rec_dot above). h state = 1 VGPR per wave. Ring
// (L1->L2 h1 transfer) remains: producer-side store off the critical
// path, consumer reads chunk-old data.
__global__ __launch_bounds__(256, 4) void lstm2_head(
    const float* __restrict__ x,
    const float* __restrict__ Wih1, const float* __restrict__ Whh1,
    const float* __restrict__ bih1, const float* __restrict__ bhh1,
    const float* __restrict__ Wih2, const float* __restrict__ Whh2,
    const float* __restrict__ bih2, const float* __restrict__ bhh2,
    const float* __restrict__ Wd1, const float* __restrict__ bd1,
    const float* __restrict__ Wd2, const float* __restrict__ bd2,
    const float* __restrict__ Wd3, const float* __restrict__ bd3,
    float* __restrict__ out)
{
    __shared__ alignas(16) float xlds[2][212];                 // [bw][padded chunk]
    __shared__ alignas(16) float ring[2][2][CHUNK_T][H_DIM];   // [bw][buf][t2][r]

    const int lane = threadIdx.x & 63;
    const int wid = __builtin_amdgcn_readfirstlane((int)(threadIdx.x >> 6));
    const int isL2 = wid >> 1;          // 0: layer-1 wave, 1: layer-2 wave
    const int bw   = wid & 1;           // batch slot within block
    const int b    = blockIdx.x * 2 + bw;

    const int r   = lane >> 2;          // hidden index 0..15
    const int gt  = lane & 3;           // 0:i 1:f 2:g(tanh) 3:o
    const int row = gt * H_DIM + r;     // row in packed 4H weights
    const int q     = r & 3;            // quad within 16-lane row
    const int rbase = r & 12;           // h-group base

    const bool is_t = (gt == 2);
    const float M   = is_t ? (-2.0f * LOG2E) : (-LOG2E);
    const float vAa = is_t ? 2.0f : 1.0f;
    const float vBc = is_t ? -1.0f : 0.0f;

    // h indices gathered per lane by rec_dot (xor order, direction-exact)
    const int idx0 = r;
    const int idx1 = rbase | (q ^ 1);
    const int idx2 = rbase | (q ^ 2);
    const int idx3 = rbase | (q ^ 3);
    // rows whose partials this lane computes (own + xor partners)
    const int rowP1 = gt * H_DIM + (r ^ 4);    // lane^16's row
    const int rowP2 = gt * H_DIM + (r ^ 8);    // lane^32's row
    const int rowP3 = gt * H_DIM + (r ^ 12);   // lane^48's row

    // ---- recurrent weights, quarter-split layout (M-scaled), pinned ----
    const float* __restrict__ Wrec = isL2 ? Whh2 : Whh1;
    v2f wq0[2], wq1[2], wq2[2], wq3[2];
    wq0[0] = (v2f){M * Wrec[row  * H_DIM + idx0], M * Wrec[row  * H_DIM + idx1]};
    wq0[1] = (v2f){M * Wrec[row  * H_DIM + idx2], M * Wrec[row  * H_DIM + idx3]};
    wq1[0] = (v2f){M * Wrec[rowP1 * H_DIM + idx0], M * Wrec[rowP1 * H_DIM + idx1]};
    wq1[1] = (v2f){M * Wrec[rowP1 * H_DIM + idx2], M * Wrec[rowP1 * H_DIM + idx3]};
    wq2[0] = (v2f){M * Wrec[rowP2 * H_DIM + idx0], M * Wrec[rowP2 * H_DIM + idx1]};
    wq2[1] = (v2f){M * Wrec[rowP2 * H_DIM + idx2], M * Wrec[rowP2 * H_DIM + idx3]};
    wq3[0] = (v2f){M * Wrec[rowP3 * H_DIM + idx0], M * Wrec[rowP3 * H_DIM + idx1]};
    wq3[1] = (v2f){M * Wrec[rowP3 * H_DIM + idx2], M * Wrec[rowP3 * H_DIM + idx3]};

    // ---- input-side weights ----
    // L1: 6 v2f over x (11 + zero pad). L2: 8 v2f over h1 (ring order).
    v2f win[8];
    float bb;
    if (!isL2) {
        #pragma unroll
        for (int j = 0; j < 5; ++j)
            win[j] = (v2f){M * Wih1[row * IN_DIM + 2 * j],
                           M * Wih1[row * IN_DIM + 2 * j + 1]};
        win[5] = (v2f){M * Wih1[row * IN_DIM + 10], 0.0f};
        win[6] = (v2f){0.f, 0.f};
        win[7] = (v2f){0.f, 0.f};
        bb = M * (bih1[row] + bhh1[row]);
    } else {
        #pragma unroll
        for (int j = 0; j < 8; ++j)
            win[j] = (v2f){M * Wih2[row * H_DIM + 2 * j],
                           M * Wih2[row * H_DIM + 2 * j + 1]};
        bb = M * (bih2[row] + bhh2[row]);
    }
    #pragma unroll
    for (int j = 0; j < 8; ++j) asm volatile("" : "+v"(win[j]));
    #pragma unroll
    for (int j = 0; j < 2; ++j) {
        asm volatile("" : "+v"(wq0[j]));
        asm volatile("" : "+v"(wq1[j]));
        asm volatile("" : "+v"(wq2[j]));
        asm volatile("" : "+v"(wq3[j]));
    }

    // bpermute byte addrs (precomputed, loop-invariant)
    const int a16 = (lane ^ 16) << 2;
    const int a32 = (lane ^ 32) << 2;
    const int a48 = (lane ^ 48) << 2;

    // x staging offsets (L1 waves): source float f -> slot (f/11)*12 + f%11
    const int f1i = lane, f2i = lane + 64, f3i = lane + 128;
    const int p1 = (f1i / IN_DIM) * ROW_PAD + (f1i % IN_DIM);
    const int p2 = (f2i / IN_DIM) * ROW_PAD + (f2i % IN_DIM);
    const int p3 = (f3i / IN_DIM) * ROW_PAD + (f3i % IN_DIM);
    const float* __restrict__ xb = x + (size_t)b * ROW_F;

    float gl0 = 0.f, gl1 = 0.f, gl2 = 0.f;
    if (!isL2) {
        if (lane < 16) xlds[bw][lane * ROW_PAD + IN_DIM] = 0.0f;  // zero pad slots
        gl0 = xb[f1i];                      // prologue: global-load chunk 0
        gl1 = xb[f2i];
        gl2 = xb[min(f3i, ROW_F - 1)];
    }

    float cst = 0.f, ssum = 0.f, hv = 0.f;  // hv: own-layer h (quad-replicated)

    for (int ck = 0; ck <= N_CHUNK; ++ck) {
        __syncthreads();                    // publish ring chunk ck-1 to L2 waves

        if (!isL2) {
            // -------- layer-1 producer: chunk ck -> ring[ck&1] --------
            if (ck < N_CHUNK) {
                float* const xbuf = &xlds[bw][0];
                xbuf[p1] = gl0;
                xbuf[p2] = gl1;
                xbuf[p3] = gl2;
                if (ck + 1 < N_CHUNK) {
                    const int base = (ck + 1) * CHUNK_F;
                    gl0 = xb[base + f1i];
                    gl1 = xb[base + f2i];
                    gl2 = xb[min(base + f3i, ROW_F - 1)];
                }
                float (* const rg)[H_DIM] = ring[bw][ck & 1];
                #pragma unroll
                for (int t2 = 0; t2 < CHUNK_T; ++t2) {
                    const float rec = rec_dot(hv, wq0, wq1, wq2, wq3, bb,
                                              a16, a32, a48);
                    const v2f* const xr = (const v2f*)(xbuf + t2 * ROW_PAD);
                    v2f xa = pk_fma(win[0], xr[0], (v2f){0.f, 0.f});
                    v2f xc = pk_fma(win[1], xr[1], (v2f){0.f, 0.f});
                    xa = pk_fma(win[2], xr[2], xa);
                    xc = pk_fma(win[3], xr[3], xc);
                    xa = pk_fma(win[4], xr[4], xa);
                    xc = pk_fma(win[5], xr[5], xc);
                    const float g = rec + (xa.x + xa.y) + (xc.x + xc.y);
                    ACT_STEP(g, cst, hv);
                    rg[t2][r] = hv;         // producer-side store (off chain)
                }
            }
        } else {
            // -------- layer-2 consumer: chunk ck-1 <- ring[(ck-1)&1] --------
            if (ck >= 1) {
                float (* const rg)[H_DIM] = ring[bw][(ck - 1) & 1];
                #pragma unroll
                for (int t2 = 0; t2 < CHUNK_T; ++t2) {
                    const float rec = rec_dot(hv, wq0, wq1, wq2, wq3, bb,
                                              a16, a32, a48);
                    const v4f* const hq = (const v4f*)&rg[t2][0];
                    const v4f q0 = hq[0];
                    const v4f q1 = hq[1];
                    const v4f q2 = hq[2];
                    const v4f q3 = hq[3];
                    v2f ya = pk_fma(win[0], (v2f){q0.x, q0.y}, (v2f){0.f, 0.f});
                    v2f yc = pk_fma(win[1], (v2f){q0.z, q0.w}, (v2f){0.f, 0.f});
                    ya = pk_fma(win[2], (v2f){q1.x, q1.y}, ya);
                    yc = pk_fma(win[3], (v2f){q1.z, q1.w}, yc);
                    ya = pk_fma(win[4], (v2f){q2.x, q2.y}, ya);
                    yc = pk_fma(win[5], (v2f){q2.z, q2.w}, yc);
                    ya = pk_fma(win[6], (v2f){q3.x, q3.y}, ya);
                    yc = pk_fma(win[7], (v2f){q3.z, q3.w}, yc);
                    const float g = rec + (ya.x + ya.y) + (yc.x + yc.y);
                    ACT_STEP(g, cst, hv);
                    ssum += __builtin_amdgcn_exp2f(LOG2E * hv);
                }
            }
        }
    }

    if (isL2) {
        // s[b,k] = exp(h2[T-1,k]) / sum_t exp(h2[t,k]); hv replicated per quad.
        const float sv = __builtin_amdgcn_exp2f(LOG2E * hv) / ssum;

        float ssb[H_DIM];
        #pragma unroll
        for (int k = 0; k < H_DIM; ++k) ssb[k] = bcast_lane(sv, 4 * k);

        // Dense head 16 -> 8 -> 8 -> 3 + softmax (one-time epilogue).
        const int r8 = lane & 7;
        float acc1 = bd1[r8];
        #pragma unroll
        for (int k = 0; k < H_DIM; ++k)
            acc1 = __builtin_fmaf(Wd1[r8 * H_DIM + k], ssb[k], acc1);

        float d1s[8];
        #pragma unroll
        for (int j = 0; j < 8; ++j) d1s[j] = bcast_lane(acc1, j);

        float acc2 = bd2[r8];
        #pragma unroll
        for (int k = 0; k < 8; ++k)
            acc2 = __builtin_fmaf(Wd2[r8 * 8 + k], d1s[k], acc2);

        float d2s[8];
        #pragma unroll
        for (int j = 0; j < 8; ++j) d2s[j] = bcast_lane(acc2, j);

        float lg = 0.f;
        if (lane < 3) {
            lg = bd3[lane];
            #pragma unroll
            for (int k = 0; k < 8; ++k)
                lg = __builtin_fmaf(Wd3[lane * 8 + k], d2s[k], lg);
        }
        const float l0 = bcast_lane(lg, 0);
        const float l1 = bcast_lane(lg, 1);
        const float l2 = bcast_lane(lg, 2);
        const float mx = fmaxf(l0, fmaxf(l1, l2));
        const float e0 = __builtin_amdgcn_exp2f(LOG2E * (l0 - mx));
        const float e1 = __builtin_amdgcn_exp2f(LOG2E * (l1 - mx));
        const float e2 = __builtin_amdgcn_exp2f(LOG2E * (l2 - mx));
        const float inv = 1.0f / (e0 + e1 + e2);
        if (lane < 3) {
            const float ev = (lane == 0) ? e0 : ((lane == 1) ? e1 : e2);
            out[b * 3 + lane] = ev * inv;
        }
    }
}

extern "C" void kernel_launch(void* const* d_in, const int* in_sizes, int n_in,
                              void* d_out, int out_size, void* d_ws, size_t ws_size,
                              hipStream_t stream) {
    (void)in_sizes; (void)n_in; (void)out_size; (void)d_ws; (void)ws_size;
    const float* x    = (const float*)d_in[0];
    const float* Wih1 = (const float*)d_in[1];
    const float* Whh1 = (const float*)d_in[2];
    const float* bih1 = (const float*)d_in[3];
    const float* bhh1 = (const float*)d_in[4];
    const float* Wih2 = (const float*)d_in[5];
    const float* Whh2 = (const float*)d_in[6];
    const float* bih2 = (const float*)d_in[7];
    const float* bhh2 = (const float*)d_in[8];
    const float* Wd1  = (const float*)d_in[9];
    const float* bd1  = (const float*)d_in[10];
    const float* Wd2  = (const float*)d_in[11];
    const float* bd2  = (const float*)d_in[12];
    const float* Wd3  = (const float*)d_in[13];
    const float* bd3  = (const float*)d_in[14];

    lstm2_head<<<dim3(4096 / 2), dim3(256), 0, stream>>>(
        x, Wih1, Whh1, bih1, bhh1, Wih2, Whh2, bih2, bhh2,
        Wd1, bd1, Wd2, bd2, Wd3, bd3, (float*)d_out);
}

// Round 6
// 473.117 us; speedup vs baseline: 1.1418x; 1.1418x over previous
//
#include <hip/hip_runtime.h>

#define T_STEPS 512
#define IN_DIM 11
#define ROW_PAD 16                  // x row padded to 16 floats (one b128 per quad lane)
#define H_DIM 16
#define ROW_F (T_STEPS * IN_DIM)    // 5632 floats per batch row
#define CHUNK_T 16                  // t-steps per x chunk
#define CHUNK_F (CHUNK_T * IN_DIM)  // 176 source floats per chunk
#define N_CHUNK (T_STEPS / CHUNK_T)
#define LOG2E 1.44269504088896340736f

typedef float v2f __attribute__((ext_vector_type(2)));
typedef float v4f __attribute__((ext_vector_type(4)));

// Packed fp32 FMA (v_pk_fma_f32): 2 MACs/instr, full rate.
__device__ __forceinline__ v2f pk_fma(v2f a, v2f b, v2f c) {
    v2f d;
    asm("v_pk_fma_f32 %0, %1, %2, %3" : "=v"(d) : "v"(a), "v"(b), "v"(c));
    return d;
}

// DPP quad_perm within each group of 4 lanes (VALU pipe, NOT LDS).
template<int CTRL>
__device__ __forceinline__ float qperm(float v) {
    return __builtin_bit_cast(float,
        __builtin_amdgcn_update_dpp(0, __builtin_bit_cast(int, v),
                                    CTRL, 0xf, 0xf, true));
}
// xor-exchange patterns within quad: [1,0,3,2]=0xB1, [2,3,0,1]=0x4E, [3,2,1,0]=0x1B

__device__ __forceinline__ float bcast_lane(float v, int l) {
    return __builtin_bit_cast(float,
        __builtin_amdgcn_readlane(__builtin_bit_cast(int, v), l));
}

// LSTM activation step: gsum -> gate act -> quad gate bcast -> cell -> h out.
#define ACT_STEP(gsum, cst, hv_out)                                           \
    {                                                                         \
        const float a_ = __builtin_fmaf(vAa,                                  \
            __builtin_amdgcn_rcpf(1.0f + __builtin_amdgcn_exp2f(gsum)), vBc); \
        const float gi_ = qperm<0x00>(a_);                                    \
        const float gf_ = qperm<0x55>(a_);                                    \
        const float gg_ = qperm<0xAA>(a_);                                    \
        const float go_ = qperm<0xFF>(a_);                                    \
        cst = __builtin_fmaf(gf_, cst, gi_ * gg_);                            \
        const float tc_ = __builtin_fmaf(2.0f,                                \
            __builtin_amdgcn_rcpf(1.0f +                                      \
                __builtin_amdgcn_exp2f(-2.0f * LOG2E * cst)), -1.0f);         \
        hv_out = go_ * tc_;                                                   \
    }

// FUSED 2-layer LSTM, one wave per batch, QUAD-SPLIT dots.
// ROUND-5 POST-MORTEM: ds_swizzle/bpermute share the LDS pipe -> 493us.
// The kernel family is LDS-pipe-pressure bound (~15-20 LDS ops/wave-step x
// 16 waves/CU ~= the 1830cyc/step wall). Fix: quad-split every 16-dot.
// Lane (r,gt) reads ONLY its 16B quartet of h / x (1 ds_read_b128 each),
// computes partial dots for the 4 rows of its quad (rows (gt^j)*16+r over
// k in {4gt..4gt+3}), then 3 quad_perm DPP xor-exchanges (VALU pipe)
// complete each row's sum. LDS ops/step: 15 -> 5. L2's two dots share one
// exchange (partials merged). Bias/M-scale folded per target row.
__global__ __launch_bounds__(256, 4) void lstm2_head(
    const float* __restrict__ x,
    const float* __restrict__ Wih1, const float* __restrict__ Whh1,
    const float* __restrict__ bih1, const float* __restrict__ bhh1,
    const float* __restrict__ Wih2, const float* __restrict__ Whh2,
    const float* __restrict__ bih2, const float* __restrict__ bhh2,
    const float* __restrict__ Wd1, const float* __restrict__ bd1,
    const float* __restrict__ Wd2, const float* __restrict__ bd2,
    const float* __restrict__ Wd3, const float* __restrict__ bd3,
    float* __restrict__ out)
{
    __shared__ alignas(16) float xlds[4][2][CHUNK_T * ROW_PAD]; // 8 KB
    __shared__ alignas(16) float shh[4][2][H_DIM];              // h slabs

    const int lane = threadIdx.x & 63;
    const int wid = __builtin_amdgcn_readfirstlane((int)(threadIdx.x >> 6));
    const int b = blockIdx.x * 4 + wid;

    const int r   = lane >> 2;          // hidden index 0..15
    const int gt  = lane & 3;           // 0:i 1:f 2:g(tanh) 3:o
    const int row = gt * H_DIM + r;     // this lane's output row in 4H

    const bool is_t = (gt == 2);
    const float vAa = is_t ? 2.0f : 1.0f;
    const float vBc = is_t ? -1.0f : 0.0f;
    const float Mown = is_t ? (-2.0f * LOG2E) : (-LOG2E);

    // ---- quad-split weights: for j=0..3, target row (gt^j)*16+r,
    //      k-quartet {4gt..4gt+3}, scaled by the TARGET row's M ----
    v2f w1h[4][2], w1x[4][2], w2h[4][2], w2i[4][2];
    #pragma unroll
    for (int j = 0; j < 4; ++j) {
        const int gj = gt ^ j;
        const float Mj = (gj == 2) ? (-2.0f * LOG2E) : (-LOG2E);
        const int rowj = gj * H_DIM + r;
        #pragma unroll
        for (int i2 = 0; i2 < 2; ++i2) {
            const int k0 = 4 * gt + 2 * i2, k1 = k0 + 1;
            w1h[j][i2] = (v2f){Mj * Whh1[rowj * H_DIM + k0],
                               Mj * Whh1[rowj * H_DIM + k1]};
            w1x[j][i2] = (v2f){k0 < IN_DIM ? Mj * Wih1[rowj * IN_DIM + k0] : 0.f,
                               k1 < IN_DIM ? Mj * Wih1[rowj * IN_DIM + k1] : 0.f};
            w2h[j][i2] = (v2f){Mj * Whh2[rowj * H_DIM + k0],
                               Mj * Whh2[rowj * H_DIM + k1]};
            w2i[j][i2] = (v2f){Mj * Wih2[rowj * H_DIM + k0],
                               Mj * Wih2[rowj * H_DIM + k1]};
        }
    }
    const float bb1 = Mown * (bih1[row] + bhh1[row]);
    const float bb2 = Mown * (bih2[row] + bhh2[row]);
    #pragma unroll
    for (int j = 0; j < 4; ++j) {
        #pragma unroll
        for (int i2 = 0; i2 < 2; ++i2) {
            asm volatile("" : "+v"(w1h[j][i2]));
            asm volatile("" : "+v"(w1x[j][i2]));
            asm volatile("" : "+v"(w2h[j][i2]));
            asm volatile("" : "+v"(w2i[j][i2]));
        }
    }

    const float* __restrict__ xb = x + (size_t)b * ROW_F;
    float* const xl0 = &xlds[wid][0][0];
    float* const xl1 = &xlds[wid][1][0];
    float* const hsl1 = &shh[wid][0][0];
    float* const hsl2 = &shh[wid][1][0];

    // zero x pad slots (cols 11..15 of every row, both buffers) - one time
    #pragma unroll
    for (int idx = 0; idx < CHUNK_T * ROW_PAD; idx += 64) {
        const int s = idx + lane;
        if ((s & 15) >= IN_DIM) { xl0[s] = 0.f; xl1[s] = 0.f; }
    }

    // staging offsets: source float f -> padded slot (f/11)*16 + f%11
    const int f1i = lane, f2i = lane + 64, f3i = lane + 128;
    const int p1 = (f1i / IN_DIM) * ROW_PAD + (f1i % IN_DIM);
    const int p2 = (f2i / IN_DIM) * ROW_PAD + (f2i % IN_DIM);
    const int p3 = (f3i / IN_DIM) * ROW_PAD + (f3i % IN_DIM);

    // prologue: global-load chunk 0
    float gl0 = xb[f1i];
    float gl1 = xb[f2i];
    float gl2 = xb[min(f3i, ROW_F - 1)];

    float c1 = 0.f, c2 = 0.f, h2v = 0.f, ssum = 0.f;
    // carried h quartets (this lane's 16B slice of each layer's h)
    v2f h1a = (v2f){0.f, 0.f}, h1b = (v2f){0.f, 0.f};
    v2f h2a = (v2f){0.f, 0.f}, h2b = (v2f){0.f, 0.f};

    const int xoff = 4 * gt;            // quartet byte offset within a row

    for (int ck = 0; ck < N_CHUNK; ++ck) {
        float* const xbuf = (ck & 1) ? xl1 : xl0;
        xbuf[p1] = gl0;
        xbuf[p2] = gl1;
        xbuf[p3] = gl2;
        if (ck + 1 < N_CHUNK) {
            const int base = (ck + 1) * CHUNK_F;
            gl0 = xb[base + f1i];
            gl1 = xb[base + f2i];
            gl2 = xb[min(base + f3i, ROW_F - 1)];
        }

        #pragma unroll
        for (int t2 = 0; t2 < CHUNK_T; ++t2) {
            // x quartet: one b128 per lane
            const v4f xq = *(const v4f*)(xbuf + t2 * ROW_PAD + xoff);
            const v2f x01 = (v2f){xq.x, xq.y};
            const v2f x23 = (v2f){xq.z, xq.w};

            // ---- L1 partials: wh1*h1(t-1) + wx*x(t), rows (gt^j)*16+r ----
            v2f d0 = pk_fma(w1h[0][0], h1a, (v2f){bb1, 0.f});
            d0 = pk_fma(w1h[0][1], h1b, d0);
            d0 = pk_fma(w1x[0][0], x01, d0);
            d0 = pk_fma(w1x[0][1], x23, d0);
            v2f d1 = pk_fma(w1h[1][0], h1a, (v2f){0.f, 0.f});
            d1 = pk_fma(w1h[1][1], h1b, d1);
            d1 = pk_fma(w1x[1][0], x01, d1);
            d1 = pk_fma(w1x[1][1], x23, d1);
            v2f d2 = pk_fma(w1h[2][0], h1a, (v2f){0.f, 0.f});
            d2 = pk_fma(w1h[2][1], h1b, d2);
            d2 = pk_fma(w1x[2][0], x01, d2);
            d2 = pk_fma(w1x[2][1], x23, d2);
            v2f d3 = pk_fma(w1h[3][0], h1a, (v2f){0.f, 0.f});
            d3 = pk_fma(w1h[3][1], h1b, d3);
            d3 = pk_fma(w1x[3][0], x01, d3);
            d3 = pk_fma(w1x[3][1], x23, d3);
            const float u0 = d0.x + d0.y;
            const float u1 = d1.x + d1.y;
            const float u2 = d2.x + d2.y;
            const float u3 = d3.x + d3.y;
            // quad all-to-all: partner j's partial for MY row (VALU DPP)
            const float g1v = u0 + qperm<0xB1>(u1)
                                 + qperm<0x4E>(u2) + qperm<0x1B>(u3);

            float h1v;
            ACT_STEP(g1v, c1, h1v);
            hsl1[r] = h1v;                              // ds_write_b32
            const v4f h1q = *(const v4f*)(hsl1 + xoff); // ds_read_b128
            h1a = (v2f){h1q.x, h1q.y};
            h1b = (v2f){h1q.z, h1q.w};

            // ---- L2 partials: wh2*h2(t-1) + wi2*h1(t), ONE exchange ----
            v2f e0 = pk_fma(w2h[0][0], h2a, (v2f){bb2, 0.f});
            e0 = pk_fma(w2h[0][1], h2b, e0);
            e0 = pk_fma(w2i[0][0], h1a, e0);
            e0 = pk_fma(w2i[0][1], h1b, e0);
            v2f e1 = pk_fma(w2h[1][0], h2a, (v2f){0.f, 0.f});
            e1 = pk_fma(w2h[1][1], h2b, e1);
            e1 = pk_fma(w2i[1][0], h1a, e1);
            e1 = pk_fma(w2i[1][1], h1b, e1);
            v2f e2 = pk_fma(w2h[2][0], h2a, (v2f){0.f, 0.f});
            e2 = pk_fma(w2h[2][1], h2b, e2);
            e2 = pk_fma(w2i[2][0], h1a, e2);
            e2 = pk_fma(w2i[2][1], h1b, e2);
            v2f e3 = pk_fma(w2h[3][0], h2a, (v2f){0.f, 0.f});
            e3 = pk_fma(w2h[3][1], h2b, e3);
            e3 = pk_fma(w2i[3][0], h1a, e3);
            e3 = pk_fma(w2i[3][1], h1b, e3);
            const float v0 = e0.x + e0.y;
            const float v1 = e1.x + e1.y;
            const float v2 = e2.x + e2.y;
            const float v3 = e3.x + e3.y;
            const float g2v = v0 + qperm<0xB1>(v1)
                                 + qperm<0x4E>(v2) + qperm<0x1B>(v3);

            ACT_STEP(g2v, c2, h2v);
            hsl2[r] = h2v;                              // ds_write_b32
            const v4f h2q = *(const v4f*)(hsl2 + xoff); // ds_read_b128
            h2a = (v2f){h2q.x, h2q.y};
            h2b = (v2f){h2q.z, h2q.w};

            ssum += __builtin_amdgcn_exp2f(LOG2E * h2v);
        }
    }

    // s[b,k] = exp(h2[T-1,k]) / sum_t exp(h2[t,k]); h2v replicated per quad.
    const float sv = __builtin_amdgcn_exp2f(LOG2E * h2v) / ssum;

    float ssb[H_DIM];
    #pragma unroll
    for (int k = 0; k < H_DIM; ++k) ssb[k] = bcast_lane(sv, 4 * k);

    // Dense head 16 -> 8 -> 8 -> 3 + softmax (one-time epilogue).
    const int r8 = lane & 7;
    float acc1 = bd1[r8];
    #pragma unroll
    for (int k = 0; k < H_DIM; ++k)
        acc1 = __builtin_fmaf(Wd1[r8 * H_DIM + k], ssb[k], acc1);

    float d1s[8];
    #pragma unroll
    for (int j = 0; j < 8; ++j) d1s[j] = bcast_lane(acc1, j);

    float acc2 = bd2[r8];
    #pragma unroll
    for (int k = 0; k < 8; ++k)
        acc2 = __builtin_fmaf(Wd2[r8 * 8 + k], d1s[k], acc2);

    float d2s[8];
    #pragma unroll
    for (int j = 0; j < 8; ++j) d2s[j] = bcast_lane(acc2, j);

    float lg = 0.f;
    if (lane < 3) {
        lg = bd3[lane];
        #pragma unroll
        for (int k = 0; k < 8; ++k)
            lg = __builtin_fmaf(Wd3[lane * 8 + k], d2s[k], lg);
    }
    const float l0 = bcast_lane(lg, 0);
    const float l1 = bcast_lane(lg, 1);
    const float l2 = bcast_lane(lg, 2);
    const float mx = fmaxf(l0, fmaxf(l1, l2));
    const float e0 = __builtin_amdgcn_exp2f(LOG2E * (l0 - mx));
    const float e1 = __builtin_amdgcn_exp2f(LOG2E * (l1 - mx));
    const float e2 = __builtin_amdgcn_exp2f(LOG2E * (l2 - mx));
    const float inv = 1.0f / (e0 + e1 + e2);
    if (lane < 3) {
        const float ev = (lane == 0) ? e0 : ((lane == 1) ? e1 : e2);
        out[b * 3 + lane] = ev * inv;
    }
}

extern "C" void kernel_launch(void* const* d_in, const int* in_sizes, int n_in,
                              void* d_out, int out_size, void* d_ws, size_t ws_size,
                              hipStream_t stream) {
    (void)in_sizes; (void)n_in; (void)out_size; (void)d_ws; (void)ws_size;
    const float* x    = (const float*)d_in[0];
    const float* Wih1 = (const float*)d_in[1];
    const float* Whh1 = (const float*)d_in[2];
    const float* bih1 = (const float*)d_in[3];
    const float* bhh1 = (const float*)d_in[4];
    const float* Wih2 = (const float*)d_in[5];
    const float* Whh2 = (const float*)d_in[6];
    const float* bih2 = (const float*)d_in[7];
    const float* bhh2 = (const float*)d_in[8];
    const float* Wd1  = (const float*)d_in[9];
    const float* bd1  = (const float*)d_in[10];
    const float* Wd2  = (const float*)d_in[11];
    const float* bd2  = (const float*)d_in[12];
    const float* Wd3  = (const float*)d_in[13];
    const float* bd3  = (const float*)d_in[14];

    lstm2_head<<<dim3(4096 / 4), dim3(256), 0, stream>>>(
        x, Wih1, Whh1, bih1, bhh1, Wih2, Whh2, bih2, bhh2,
        Wd1, bd1, Wd2, bd2, Wd3, bd3, (float*)d_out);
}